// Round 21
// baseline (615.005 us; speedup 1.0000x reference)
//
#include <hip/hip_runtime.h>
#include <math.h>

static constexpr int H = 256, W = 256, HW = H * W;
static constexpr int PW = 258;
static constexpr size_t PREC = 66564;   // 258*258 padded px

typedef __attribute__((ext_vector_type(8))) _Float16 half8v;  // 16B
typedef __attribute__((ext_vector_type(4))) _Float16 half4v;  // 8B
typedef __attribute__((ext_vector_type(4))) float  float4v;   // MFMA acc

__device__ __forceinline__ half8v h8zero() {
  half8v z;
  #pragma unroll
  for (int i = 0; i < 8; ++i) z[i] = (_Float16)0;
  return z;
}

// global_load_lds: per-lane global src (16B), wave-uniform LDS base; lane i -> base + i*16.
__device__ __forceinline__ void gload_lds16(const _Float16* g, _Float16* lds) {
  __builtin_amdgcn_global_load_lds(
      (const __attribute__((address_space(1))) void*)g,
      (__attribute__((address_space(3))) void*)lds, 16, 0, 0);
}

// ---------- activations ----------
__device__ __forceinline__ float gelu_f(float v) {
  return 0.5f * v * (1.0f + erff(v * 0.70710678118654752440f));
}
template<int ACT>
__device__ __forceinline__ float apply_act(float v) {
  if constexpr (ACT == 1) return v >= 0.f ? v : 0.1f * v;   // LeakyReLU(0.1)
  if constexpr (ACT == 2) return gelu_f(v);
  return v;
}

// ---------- zero 1-px borders, REC=64 packed buffers (4 bufs x 2 batches) ----------
__global__ __launch_bounds__(256)
void zero_border64_k(_Float16* p0, _Float16* p1, _Float16* p2, _Float16* p3)
{
  int t = blockIdx.x * 256 + threadIdx.x;
  if (t >= 1028) return;
  int inst = blockIdx.y;
  _Float16* P = (inst >> 1) == 0 ? p0 : ((inst >> 1) == 1 ? p1 : ((inst >> 1) == 2 ? p2 : p3));
  int b = inst & 1;
  int y, x;
  if      (t < 258) { y = 0;        x = t; }
  else if (t < 516) { y = 257;      x = t - 258; }
  else if (t < 772) { y = t - 515;  x = 0; }
  else              { y = t - 771;  x = 257; }
  _Float16* o = P + ((size_t)b * PREC + (size_t)y * PW + x) * 64;
  half8v z = h8zero();
  #pragma unroll
  for (int j = 0; j < 8; ++j) *(half8v*)&o[j * 8] = z;
}

// ---------- zero 1-px borders, REC=32 packed buffers (4 bufs x 2 batches; per-buf batch stride in recs) ----------
__global__ __launch_bounds__(256)
void zero_border32_k(_Float16* p0, size_t s0, _Float16* p1, size_t s1,
                     _Float16* p2, size_t s2, _Float16* p3, size_t s3)
{
  int t = blockIdx.x * 256 + threadIdx.x;
  if (t >= 1028) return;
  int inst = blockIdx.y;
  _Float16* P; size_t bs;
  switch (inst >> 1) {
    case 0: P = p0; bs = s0; break;
    case 1: P = p1; bs = s1; break;
    case 2: P = p2; bs = s2; break;
    default: P = p3; bs = s3; break;
  }
  int b = inst & 1;
  int y, x;
  if      (t < 258) { y = 0;        x = t; }
  else if (t < 516) { y = 257;      x = t - 258; }
  else if (t < 772) { y = t - 515;  x = 0; }
  else              { y = t - 771;  x = 257; }
  _Float16* o = P + ((size_t)b * bs + (size_t)y * PW + x) * 32;
  half8v z = h8zero();
  #pragma unroll
  for (int j = 0; j < 4; ++j) *(half8v*)&o[j * 8] = z;
}

// ---------- pack x,key: NCHW f32 -> packed-padded [B][258][258][64]: hi(0..31)+lo(32..63) ----------
__global__ __launch_bounds__(256)
void pack2_k(const float* __restrict__ inA, _Float16* __restrict__ pA,
             const float* __restrict__ inB, _Float16* __restrict__ pB)
{
  const int p = blockIdx.x * 256 + threadIdx.x;
  const int b = blockIdx.y;
  const float* in = blockIdx.z ? inB : inA;
  _Float16* P = blockIdx.z ? pB : pA;
  const float* ip = in + (size_t)b * 32 * HW + p;
  __attribute__((aligned(16))) _Float16 hv[32], lv[32];
  #pragma unroll
  for (int c = 0; c < 32; ++c) {
    float v = ip[(size_t)c * HW];
    _Float16 h = (_Float16)v;
    hv[c] = h;
    lv[c] = (_Float16)((v - (float)h) * 2048.0f);
  }
  const int y = p >> 8, xcol = p & 255;
  _Float16* o = P + ((size_t)b * PREC + (size_t)(y + 1) * PW + xcol + 1) * 64;
  #pragma unroll
  for (int j = 0; j < 4; ++j) {
    *(half8v*)&o[j * 8]      = *(half8v*)&hv[j * 8];
    *(half8v*)&o[32 + j * 8] = *(half8v*)&lv[j * 8];
  }
}

// ---------- weight prep x3: [OC][CIN][3][3] f32 -> [tap][OC][CIN] f16 hi + scaled lo ----------
__device__ __forceinline__ void prep_w_body(const float* w, _Float16* hi, _Float16* lo,
                                            int OC, int CIN, int tid)
{
  if (tid >= OC * CIN * 9) return;
  int ci = tid % CIN; int r = tid / CIN; int oc = r % OC; int tap = r / OC;
  float v = w[((size_t)oc * CIN + ci) * 9 + tap];
  _Float16 h = (_Float16)v;
  hi[tid] = h;
  lo[tid] = (_Float16)((v - (float)h) * 2048.0f);
}
__global__ __launch_bounds__(256)
void prep3_w_k(const float* __restrict__ w0, _Float16* __restrict__ h0, _Float16* __restrict__ l0, int OC0, int CIN0, int nb0,
               const float* __restrict__ w1, _Float16* __restrict__ h1, _Float16* __restrict__ l1, int OC1, int CIN1, int nb1,
               const float* __restrict__ w2, _Float16* __restrict__ h2, _Float16* __restrict__ l2, int OC2, int CIN2)
{
  int bb = blockIdx.x;
  if (bb < nb0)            prep_w_body(w0, h0, l0, OC0, CIN0, bb * 256 + threadIdx.x);
  else if (bb < nb0 + nb1) prep_w_body(w1, h1, l1, OC1, CIN1, (bb - nb0) * 256 + threadIdx.x);
  else                     prep_w_body(w2, h2, l2, OC2, CIN2, (bb - nb0 - nb1) * 256 + threadIdx.x);
}

// ---------- 3x3 conv, f16 MFMA; packed-padded inputs, gll staging ----------
// r20 diagnosis: per wave-tap, 8 ds_read_b128 = 96 CU-LDS-cy vs 24 MFMA = 29
// CU-matrix-cy -> LDS-pipe-bound 3.3x, MfmaUtil capped ~30% (matches 27-28%
// measured r17-r20, occupancy-insensitive). Lever: amortize B reads over more
// output channels -> dcn OCB=48 (ratio 96:43.5, cap ~45%), t3 OCB=128
// (48:38.8, cap ~80%). OC=32 kernels are capped at OCB=32 (whole tensor).
// SPLIT=3 (pre-topk): [.][258][258][64] hi+lo records; 48 gll tasks + edge copies.
// SPLIT=1 (tail): [.][258][258][32] hi records; 24 gll tasks + edge copies.
// OMODE: 0 = NCHW f32 out, 1 = packed-padded hi/lo out, 3 = NHWC f16 hi only.
// MFMA 16x16x32 f16 (HW-verified r5-r20): A row=l&15 (oc), k=(l>>4)*8+j;
//   B col=l&15 (px); D col=l&15 (px), row=(l>>4)*4+reg (oc).
template<int CIN, int OC, int OCB, int ACT, int OMODE, int SPLIT>
__global__ __launch_bounds__(256)
void conv3x3_mfma_k(const _Float16* __restrict__ iH0, const _Float16* __restrict__ iL0,
                    const _Float16* __restrict__ iH1, const _Float16* __restrict__ iL1, int cin0,
                    const _Float16* __restrict__ wHi, const _Float16* __restrict__ wLo,
                    const float* __restrict__ bias,
                    float* __restrict__ outF, _Float16* __restrict__ oH, _Float16* __restrict__ oL)
{
  constexpr int NOF  = OCB / 16;
  constexpr int NAQ  = (SPLIT == 3) ? NOF : 1;
  constexpr int REC  = (SPLIT == 3) ? 64 : 32;
  constexpr int nOcg = OC / OCB;
  __shared__ _Float16 sB[6 * 66 * REC];

  const int l  = threadIdx.x & 63;
  const int wv = threadIdx.x >> 6;

  const int bid = blockIdx.x;
  const int xcd = bid & 7, q = bid >> 3;
  const int ocg  = q % nOcg;
  const int tIdx = (q / nOcg) * 8 + xcd;
  const int b   = tIdx >> 8;
  const int x0  = ((tIdx >> 6) & 3) * 64;
  const int y0  = (tIdx & 63) * 4;
  const int oc0 = ocg * OCB;

  float4v accP[NOF][4];
  float4v accQ[NAQ][4];
  #pragma unroll
  for (int j = 0; j < NOF; ++j)
    #pragma unroll
    for (int f = 0; f < 4; ++f)
      accP[j][f] = (float4v){0.f, 0.f, 0.f, 0.f};
  #pragma unroll
  for (int j = 0; j < NAQ; ++j)
    #pragma unroll
    for (int f = 0; f < 4; ++f)
      accQ[j][f] = (float4v){0.f, 0.f, 0.f, 0.f};

  const int k8  = (l >> 4) * 8;
  const int ocl = l & 15;
  const int rowy = y0 + wv;

  #pragma unroll 1
  for (int cc = 0; cc < CIN; cc += 32) {
    if constexpr (SPLIT == 3) {
      const _Float16* cb = (cc < cin0 ? iH0 : iH1) + (size_t)b * (PREC * 64);
      __syncthreads();
      // 48 gll tasks: 6 rows x 8 px-groups (8 px x 8 slots); 12 per wave
      #pragma unroll
      for (int k = 0; k < 12; ++k) {
        int t = wv + 4 * k;
        int r = t >> 3, s = t & 7;
        const _Float16* src = cb
            + (((size_t)(y0 + r) * PW) + (x0 + s * 8 + (l >> 3))) * 64
            + ((l & 7) ^ (l >> 3)) * 8;
        gload_lds16(src, &sB[(r * 66 + s * 8) * 64]);
      }
      #pragma unroll
      for (int rr = wv; rr < 6; rr += 4) {
        if (l < 16) {
          int pxo = l >> 3, slot = l & 7;
          const _Float16* src = cb
              + (((size_t)(y0 + rr) * PW) + (x0 + 64 + pxo)) * 64 + (slot ^ pxo) * 8;
          half8v v = *(const half8v*)src;
          *(half8v*)&sB[(rr * 66 + 64 + pxo) * 64 + slot * 8] = v;
        }
      }
      __syncthreads();
    } else {
      const _Float16* cb = iH0 + (size_t)(b * (CIN >> 5) + (cc >> 5)) * (PREC * 32);
      __syncthreads();
      // 24 gll tasks: 6 rows x 4 px-groups (16 px x 4 slots); 6 per wave
      #pragma unroll
      for (int k = 0; k < 6; ++k) {
        int t = wv + 4 * k;
        int r = t >> 2, s = t & 3;
        const _Float16* src = cb
            + (((size_t)(y0 + r) * PW) + (x0 + s * 16 + (l >> 2))) * 32
            + ((l & 3) ^ ((l >> 2) & 3)) * 8;
        gload_lds16(src, &sB[(r * 66 + s * 16) * 32]);
      }
      #pragma unroll
      for (int rr = wv; rr < 6; rr += 4) {
        if (l < 8) {
          int pxo = l >> 2, slot = l & 3;
          const _Float16* src = cb
              + (((size_t)(y0 + rr) * PW) + (x0 + 64 + pxo)) * 32 + (slot ^ pxo) * 8;
          half8v v = *(const half8v*)src;
          *(half8v*)&sB[(rr * 66 + 64 + pxo) * 32 + slot * 8] = v;
        }
      }
      __syncthreads();
    }

    #pragma unroll 1
    for (int tap = 0; tap < 9; ++tap) {
      const int dy = tap / 3, dx = tap - 3 * (tap / 3);
      half8v ah[NOF], aq[NAQ];
      const _Float16* hp = wHi + ((size_t)tap * OC + oc0 + ocl) * CIN + cc + k8;
      #pragma unroll
      for (int j = 0; j < NOF; ++j)
        ah[j] = *(const half8v*)(hp + (size_t)j * 16 * CIN);
      if constexpr (SPLIT == 3) {
        const _Float16* lp = wLo + ((size_t)tap * OC + oc0 + ocl) * CIN + cc + k8;
        #pragma unroll
        for (int j = 0; j < NOF; ++j)
          aq[j] = *(const half8v*)(lp + (size_t)j * 16 * CIN);
      }
      const int px = ocl + dx;
      if constexpr (SPLIT == 3) {
        const int rbase = ((wv + dy) * 66 + px) * 64;
        const int clsH = (l >> 4) ^ (px & 7);
        const int clsQ = ((l >> 4) + 4) ^ (px & 7);
        #pragma unroll
        for (int f = 0; f < 4; ++f) {
          half8v bh = *(const half8v*)&sB[rbase + f * 1024 + clsH * 8];
          half8v bq = *(const half8v*)&sB[rbase + f * 1024 + clsQ * 8];
          #pragma unroll
          for (int j = 0; j < NOF; ++j) {
            accP[j][f] = __builtin_amdgcn_mfma_f32_16x16x32_f16(ah[j], bh, accP[j][f], 0, 0, 0);
            accQ[j][f] = __builtin_amdgcn_mfma_f32_16x16x32_f16(ah[j], bq, accQ[j][f], 0, 0, 0);
            accQ[j][f] = __builtin_amdgcn_mfma_f32_16x16x32_f16(aq[j], bh, accQ[j][f], 0, 0, 0);
          }
        }
      } else {
        const int rbase = ((wv + dy) * 66 + px) * 32;
        const int clsH = ((l >> 4) ^ px) & 3;
        #pragma unroll
        for (int f = 0; f < 4; ++f) {
          half8v bh = *(const half8v*)&sB[rbase + f * 512 + clsH * 8];
          #pragma unroll
          for (int j = 0; j < NOF; ++j)
            accP[j][f] = __builtin_amdgcn_mfma_f32_16x16x32_f16(ah[j], bh, accP[j][f], 0, 0, 0);
        }
      }
    }
  }

  // ---- epilogue: D col=l&15 (px), row=(l>>4)*4+reg (oc) ----
  #pragma unroll
  for (int j = 0; j < NOF; ++j)
    #pragma unroll
    for (int f = 0; f < 4; ++f) {
      const int px  = x0 + f * 16 + ocl;
      const int occ = oc0 + j * 16 + (l >> 4) * 4;
      float vv4[4];
      #pragma unroll
      for (int r = 0; r < 4; ++r) {
        float bv = bias ? bias[occ + r] : 0.f;
        float vv = accP[j][f][r] + bv;
        if constexpr (SPLIT == 3) vv += accQ[j][f][r] * (1.0f / 2048.0f);
        vv4[r] = apply_act<ACT>(vv);
      }
      if constexpr (OMODE == 0) {
        #pragma unroll
        for (int r = 0; r < 4; ++r)
          outF[((size_t)(b * OC + occ + r) * H + rowy) * W + px] = vv4[r];
      } else if constexpr (OMODE == 1) {
        __attribute__((aligned(8))) _Float16 hv[4], lv[4];
        #pragma unroll
        for (int r = 0; r < 4; ++r) {
          _Float16 h = (_Float16)vv4[r];
          hv[r] = h;
          lv[r] = (_Float16)((vv4[r] - (float)h) * 2048.0f);
        }
        size_t rec = (size_t)b * PREC + (size_t)(rowy + 1) * PW + px + 1;
        *(half4v*)&oH[rec * 64 + occ]      = *(half4v*)&hv[0];
        *(half4v*)&oH[rec * 64 + 32 + occ] = *(half4v*)&lv[0];
      } else {
        __attribute__((aligned(8))) _Float16 hv[4];
        #pragma unroll
        for (int r = 0; r < 4; ++r) hv[r] = (_Float16)vv4[r];
        size_t ob = ((size_t)b * HW + (size_t)rowy * W + px) * OC + occ;
        *(half4v*)&oH[ob] = *(half4v*)&hv[0];
      }
    }
}

// ---------- 1x1 conv: NHWC f16 in -> packed-padded chunked f16 hi out ----------
template<int CIN, int OCB, int ACT>
__global__ __launch_bounds__(256)
void conv1x1_nhwc_k(const _Float16* __restrict__ in, const float* __restrict__ w,
                    _Float16* __restrict__ oP, int OC)
{
  __shared__ __align__(16) float sW[OCB][CIN];
  const int b   = blockIdx.y;
  const int oc0 = blockIdx.z * OCB;
  for (int t = threadIdx.x; t < OCB * CIN; t += 256)
    sW[t / CIN][t % CIN] = w[(size_t)(oc0 + t / CIN) * CIN + (t % CIN)];
  __syncthreads();

  const int pb = blockIdx.x * 1024 + threadIdx.x;    // 4 px at stride 256
  float acc[OCB][4];
  #pragma unroll
  for (int o = 0; o < OCB; ++o)
    #pragma unroll
    for (int i = 0; i < 4; ++i) acc[o][i] = 0.f;

  #pragma unroll 1
  for (int c0 = 0; c0 < CIN; c0 += 8) {
    float v[4][8];
    #pragma unroll
    for (int i = 0; i < 4; ++i) {
      const _Float16* ip = in + ((size_t)b * HW + pb + i * 256) * CIN + c0;
      half8v hv8 = *(const half8v*)ip;
      #pragma unroll
      for (int j = 0; j < 8; ++j) v[i][j] = (float)hv8[j];
    }
    #pragma unroll
    for (int o = 0; o < OCB; ++o) {
      const float4 w0 = *(const float4*)&sW[o][c0];
      const float4 w1 = *(const float4*)&sW[o][c0 + 4];
      #pragma unroll
      for (int i = 0; i < 4; ++i) {
        acc[o][i] += v[i][0]*w0.x + v[i][1]*w0.y + v[i][2]*w0.z + v[i][3]*w0.w
                   + v[i][4]*w1.x + v[i][5]*w1.y + v[i][6]*w1.z + v[i][7]*w1.w;
      }
    }
  }
  #pragma unroll
  for (int i = 0; i < 4; ++i) {
    __attribute__((aligned(16))) _Float16 hv[OCB];
    #pragma unroll
    for (int o = 0; o < OCB; ++o)
      hv[o] = (_Float16)apply_act<ACT>(acc[o][i]);
    int p = pb + i * 256;
    int y = p >> 8, xcol = p & 255;
    size_t rec = (size_t)(b * (OC >> 5) + (oc0 >> 5)) * PREC + (size_t)(y + 1) * PW + xcol + 1;
    #pragma unroll
    for (int j = 0; j < OCB / 8; ++j)
      *(half8v*)&oP[rec * 32 + (oc0 & 31) + j * 8] = *(half8v*)&hv[j * 8];
  }
}

// ---------- corr + top-3, 2 px/thread float2 (jax tie-break: lower index wins) ----------
__global__ __launch_bounds__(256)
void corr_topk_k(const float* __restrict__ warp, const float* __restrict__ x,
                 int* __restrict__ idxo)
{
  const int p2 = (blockIdx.x * 256 + threadIdx.x) * 2;
  const int b = blockIdx.y;
  float corr[9][2];
  #pragma unroll
  for (int o = 0; o < 9; ++o) { corr[o][0] = 0.f; corr[o][1] = 0.f; }
  #pragma unroll 1
  for (int c = 0; c < 32; ++c) {
    float2 xv = *(const float2*)&x[((size_t)b * 32 + c) * HW + p2];
    const float* wp = warp + ((size_t)b * 288 + (size_t)c * 9) * HW + p2;
    #pragma unroll
    for (int o = 0; o < 9; ++o) {
      float2 wv = *(const float2*)&wp[(size_t)o * HW];
      corr[o][0] += wv.x * xv.x;
      corr[o][1] += wv.y * xv.y;
    }
  }
  int2 packs;
  #pragma unroll
  for (int i = 0; i < 2; ++i) {
    unsigned mask = 0;
    int packed = 0;
    #pragma unroll
    for (int t = 0; t < 3; ++t) {
      float best = -INFINITY; int bi = 0;
      #pragma unroll
      for (int o = 0; o < 9; ++o) {
        bool take = (((mask >> o) & 1u) == 0u) && (corr[o][i] > best);
        best = take ? corr[o][i] : best;
        bi   = take ? o          : bi;
      }
      mask   |= 1u << bi;
      packed |= bi << (4 * t);
    }
    ((int*)&packs)[i] = packed;
  }
  *(int2*)&idxo[(size_t)b * HW + p2] = packs;
}

// ---------- gather selected warps + 3x3 conv with w_sel; out packed-padded f16 hi ----------
__global__ __launch_bounds__(256)
void selconv_k(const float* __restrict__ warp, const int* __restrict__ idxp,
               const float* __restrict__ wsel, const float* __restrict__ bsel,
               _Float16* __restrict__ oP)
{
  const int tx = threadIdx.x & 31, ty = threadIdx.x >> 5;
  const int px = blockIdx.x * 32 + tx;
  const int py = blockIdx.y * 8 + ty;
  const int b  = blockIdx.z;

  int  nidx[9];
  bool nval[9];
  int  qoff[9];
  #pragma unroll
  for (int kh = 0; kh < 3; ++kh)
    #pragma unroll
    for (int kw = 0; kw < 3; ++kw) {
      int k = kh * 3 + kw;
      int qy = py + kh - 1, qx = px + kw - 1;
      nval[k] = (qy >= 0 && qy < H && qx >= 0 && qx < W);
      qoff[k] = qy * W + qx;
      nidx[k] = nval[k] ? idxp[(size_t)b * HW + qoff[k]] : 0;
    }

  float ws27[27];
  #pragma unroll
  for (int i = 0; i < 27; ++i) ws27[i] = wsel[i];
  const float bs = bsel[0];

  float arr[32];
  #pragma unroll 1
  for (int c = 0; c < 32; ++c) {
    float acc = bs;
    const float* wb = warp + ((size_t)b * 288 + (size_t)c * 9) * HW;
    #pragma unroll
    for (int k = 0; k < 9; ++k) {
      if (nval[k]) {
        int pk = nidx[k];
        #pragma unroll
        for (int t = 0; t < 3; ++t) {
          int o = (pk >> (4 * t)) & 15;
          acc += ws27[t * 9 + k] * wb[(size_t)o * HW + qoff[k]];
        }
      }
    }
    arr[c] = acc;
  }

  __attribute__((aligned(16))) _Float16 hv[32];
  #pragma unroll
  for (int c = 0; c < 32; ++c) hv[c] = (_Float16)arr[c];
  size_t rec = (size_t)b * PREC + (size_t)(py + 1) * PW + px + 1;
  #pragma unroll
  for (int j = 0; j < 4; ++j)
    *(half8v*)&oP[rec * 32 + j * 8] = *(half8v*)&hv[j * 8];
}

// ---------- launch ----------
extern "C" void kernel_launch(void* const* d_in, const int* in_sizes, int n_in,
                              void* d_out, int out_size, void* d_ws, size_t ws_size,
                              hipStream_t stream) {
  const float* x      = (const float*)d_in[0];
  const float* key    = (const float*)d_in[1];
  const float* w_off1 = (const float*)d_in[2];
  const float* b_off1 = (const float*)d_in[3];
  const float* w_off2 = (const float*)d_in[4];
  const float* b_off2 = (const float*)d_in[5];
  const float* w_dcn  = (const float*)d_in[6];
  const float* b_dcn  = (const float*)d_in[7];
  const float* w_sel  = (const float*)d_in[8];
  const float* b_sel  = (const float*)d_in[9];
  const float* w_t1   = (const float*)d_in[10];
  const float* w_t2   = (const float*)d_in[11];
  const float* w_t3   = (const float*)d_in[12];
  const float* w_t4   = (const float*)d_in[13];
  const float* w_t5   = (const float*)d_in[14];

  // ---- workspace layout (peak ~185.74 MB; proven r17-r20) ----
  char* ws = (char*)d_ws;
  float* warp = (float*)(ws);                                // [2,288,HW] f32, [0, 150994944)
  _Float16* xP   = (_Float16*)(ws);                          // [0, 17040384)
  _Float16* o1P  = (_Float16*)(ws + 17040384);               // [17040384, 34080768)
  _Float16* w1H  = (_Float16*)(ws + 34080768);
  _Float16* w1L  = w1H + 18432;
  _Float16* w2H  = w1L + 18432;
  _Float16* w2L  = w2H + 9216;
  _Float16* wdH  = (_Float16*)(ws + 150994944);
  _Float16* wdL  = wdH + 165888;
  _Float16* keyP = (_Float16*)(ws + 151658496);
  _Float16* o2P  = (_Float16*)(ws + 168698880);
  int*      idxb = (int*)(ws + 150994944);
  _Float16* kwP  = (_Float16*)(ws + 151658496);
  _Float16* twB  = (_Float16*)(ws + 160178688);
  _Float16* t1H_w = twB;
  _Float16* t1L_w = twB + 9216;
  _Float16* t3H_w = twB + 18432;
  _Float16* t3L_w = twB + 165888;
  _Float16* t5H_w = twB + 313344;
  _Float16* t5L_w = twB + 322560;
  _Float16* y1  = (_Float16*)(ws);
  _Float16* t2P = (_Float16*)(ws + 16777216);
  _Float16* t4P = (_Float16*)(ws + 58720256);
  _Float16* y3  = (_Float16*)(ws + 83886080);
  float* out = (float*)d_out;

  dim3 blk(256);

  zero_border64_k<<<dim3(5, 8), blk, 0, stream>>>(xP, keyP, o1P, o2P);
  pack2_k<<<dim3(256, 2, 2), blk, 0, stream>>>(x, xP, key, keyP);
  prep3_w_k<<<dim3(756), blk, 0, stream>>>(
      w_off1, w1H, w1L, 32, 64, 72,
      w_off2, w2H, w2L, 32, 32, 36,
      w_dcn,  wdH, wdL, 288, 64);

  conv3x3_mfma_k<64, 32, 32, 1, 1, 3><<<dim3(512), blk, 0, stream>>>(
      xP, nullptr, keyP, nullptr, 32, w1H, w1L, b_off1, nullptr, o1P, nullptr);
  conv3x3_mfma_k<32, 32, 32, 1, 1, 3><<<dim3(512), blk, 0, stream>>>(
      o1P, nullptr, nullptr, nullptr, 32, w2H, w2L, b_off2, nullptr, o2P, nullptr);
  // dcn: OCB=48 (288/48 = 6 groups; grid 6*512 = 3072, %8==0 bijective)
  conv3x3_mfma_k<64, 288, 48, 0, 0, 3><<<dim3(3072), blk, 0, stream>>>(
      keyP, nullptr, o2P, nullptr, 32, wdH, wdL, b_dcn, warp, nullptr, nullptr);
  corr_topk_k<<<dim3(128, 2), blk, 0, stream>>>(warp, x, idxb);
  zero_border32_k<<<dim3(5, 2), blk, 0, stream>>>(kwP, PREC, kwP, PREC, kwP, PREC, kwP, PREC);
  selconv_k<<<dim3(8, 32, 2), blk, 0, stream>>>(warp, idxb, w_sel, b_sel, kwP);

  zero_border32_k<<<dim3(5, 8), blk, 0, stream>>>(
      t2P, 4 * PREC, t2P + PREC * 32, 4 * PREC, t2P + 2 * PREC * 32, 4 * PREC, t2P + 3 * PREC * 32, 4 * PREC);
  zero_border32_k<<<dim3(5, 2), blk, 0, stream>>>(t4P, PREC, t4P, PREC, t4P, PREC, t4P, PREC);
  prep3_w_k<<<dim3(648), blk, 0, stream>>>(
      w_t1, t1H_w, t1L_w, 32, 32, 36,
      w_t3, t3H_w, t3L_w, 128, 128, 576,
      w_t5, t5H_w, t5L_w, 32, 32);

  conv3x3_mfma_k<32, 32, 32, 2, 3, 1><<<dim3(512), blk, 0, stream>>>(
      kwP, nullptr, nullptr, nullptr, 32, t1H_w, t1L_w, nullptr, nullptr, y1, nullptr);
  conv1x1_nhwc_k<32, 16, 2><<<dim3(64, 2, 8), blk, 0, stream>>>(y1, w_t2, t2P, 128);
  // t3: OCB=128 (single oc-group; grid 512, %8==0)
  conv3x3_mfma_k<128, 128, 128, 2, 3, 1><<<dim3(512), blk, 0, stream>>>(
      t2P, nullptr, nullptr, nullptr, 128, t3H_w, t3L_w, nullptr, nullptr, y3, nullptr);
  conv1x1_nhwc_k<128, 16, 2><<<dim3(64, 2, 2), blk, 0, stream>>>(y3, w_t4, t4P, 32);
  conv3x3_mfma_k<32, 32, 32, 0, 0, 1><<<dim3(512), blk, 0, stream>>>(
      t4P, nullptr, nullptr, nullptr, 32, t5H_w, t5L_w, nullptr, out, nullptr, nullptr);
}

// Round 22
// 600.332 us; speedup vs baseline: 1.0244x; 1.0244x over previous
//
#include <hip/hip_runtime.h>
#include <math.h>

static constexpr int H = 256, W = 256, HW = H * W;
static constexpr int PW = 258;
static constexpr size_t PREC = 66564;   // 258*258 padded px

typedef __attribute__((ext_vector_type(8))) _Float16 half8v;  // 16B
typedef __attribute__((ext_vector_type(4))) _Float16 half4v;  // 8B
typedef __attribute__((ext_vector_type(4))) float  float4v;   // MFMA acc

__device__ __forceinline__ half8v h8zero() {
  half8v z;
  #pragma unroll
  for (int i = 0; i < 8; ++i) z[i] = (_Float16)0;
  return z;
}

// global_load_lds: per-lane global src (16B), wave-uniform LDS base; lane i -> base + i*16.
__device__ __forceinline__ void gload_lds16(const _Float16* g, _Float16* lds) {
  __builtin_amdgcn_global_load_lds(
      (const __attribute__((address_space(1))) void*)g,
      (__attribute__((address_space(3))) void*)lds, 16, 0, 0);
}

// ---------- activations ----------
__device__ __forceinline__ float gelu_f(float v) {
  return 0.5f * v * (1.0f + erff(v * 0.70710678118654752440f));
}
template<int ACT>
__device__ __forceinline__ float apply_act(float v) {
  if constexpr (ACT == 1) return v >= 0.f ? v : 0.1f * v;   // LeakyReLU(0.1)
  if constexpr (ACT == 2) return gelu_f(v);
  return v;
}

// ---------- zero 1-px borders, REC=64 packed buffers (4 bufs x 2 batches) ----------
__global__ __launch_bounds__(256)
void zero_border64_k(_Float16* p0, _Float16* p1, _Float16* p2, _Float16* p3)
{
  int t = blockIdx.x * 256 + threadIdx.x;
  if (t >= 1028) return;
  int inst = blockIdx.y;
  _Float16* P = (inst >> 1) == 0 ? p0 : ((inst >> 1) == 1 ? p1 : ((inst >> 1) == 2 ? p2 : p3));
  int b = inst & 1;
  int y, x;
  if      (t < 258) { y = 0;        x = t; }
  else if (t < 516) { y = 257;      x = t - 258; }
  else if (t < 772) { y = t - 515;  x = 0; }
  else              { y = t - 771;  x = 257; }
  _Float16* o = P + ((size_t)b * PREC + (size_t)y * PW + x) * 64;
  half8v z = h8zero();
  #pragma unroll
  for (int j = 0; j < 8; ++j) *(half8v*)&o[j * 8] = z;
}

// ---------- zero 1-px borders, REC=32 packed buffers (4 bufs x 2 batches; per-buf batch stride in recs) ----------
__global__ __launch_bounds__(256)
void zero_border32_k(_Float16* p0, size_t s0, _Float16* p1, size_t s1,
                     _Float16* p2, size_t s2, _Float16* p3, size_t s3)
{
  int t = blockIdx.x * 256 + threadIdx.x;
  if (t >= 1028) return;
  int inst = blockIdx.y;
  _Float16* P; size_t bs;
  switch (inst >> 1) {
    case 0: P = p0; bs = s0; break;
    case 1: P = p1; bs = s1; break;
    case 2: P = p2; bs = s2; break;
    default: P = p3; bs = s3; break;
  }
  int b = inst & 1;
  int y, x;
  if      (t < 258) { y = 0;        x = t; }
  else if (t < 516) { y = 257;      x = t - 258; }
  else if (t < 772) { y = t - 515;  x = 0; }
  else              { y = t - 771;  x = 257; }
  _Float16* o = P + ((size_t)b * bs + (size_t)y * PW + x) * 32;
  half8v z = h8zero();
  #pragma unroll
  for (int j = 0; j < 4; ++j) *(half8v*)&o[j * 8] = z;
}

// ---------- pack x,key: NCHW f32 -> packed-padded [B][258][258][64]: hi(0..31)+lo(32..63) ----------
__global__ __launch_bounds__(256)
void pack2_k(const float* __restrict__ inA, _Float16* __restrict__ pA,
             const float* __restrict__ inB, _Float16* __restrict__ pB)
{
  const int p = blockIdx.x * 256 + threadIdx.x;
  const int b = blockIdx.y;
  const float* in = blockIdx.z ? inB : inA;
  _Float16* P = blockIdx.z ? pB : pA;
  const float* ip = in + (size_t)b * 32 * HW + p;
  __attribute__((aligned(16))) _Float16 hv[32], lv[32];
  #pragma unroll
  for (int c = 0; c < 32; ++c) {
    float v = ip[(size_t)c * HW];
    _Float16 h = (_Float16)v;
    hv[c] = h;
    lv[c] = (_Float16)((v - (float)h) * 2048.0f);
  }
  const int y = p >> 8, xcol = p & 255;
  _Float16* o = P + ((size_t)b * PREC + (size_t)(y + 1) * PW + xcol + 1) * 64;
  #pragma unroll
  for (int j = 0; j < 4; ++j) {
    *(half8v*)&o[j * 8]      = *(half8v*)&hv[j * 8];
    *(half8v*)&o[32 + j * 8] = *(half8v*)&lv[j * 8];
  }
}

// ---------- weight prep x3: [OC][CIN][3][3] f32 -> [tap][OC][CIN] f16 hi + scaled lo ----------
__device__ __forceinline__ void prep_w_body(const float* w, _Float16* hi, _Float16* lo,
                                            int OC, int CIN, int tid)
{
  if (tid >= OC * CIN * 9) return;
  int ci = tid % CIN; int r = tid / CIN; int oc = r % OC; int tap = r / OC;
  float v = w[((size_t)oc * CIN + ci) * 9 + tap];
  _Float16 h = (_Float16)v;
  hi[tid] = h;
  lo[tid] = (_Float16)((v - (float)h) * 2048.0f);
}
__global__ __launch_bounds__(256)
void prep3_w_k(const float* __restrict__ w0, _Float16* __restrict__ h0, _Float16* __restrict__ l0, int OC0, int CIN0, int nb0,
               const float* __restrict__ w1, _Float16* __restrict__ h1, _Float16* __restrict__ l1, int OC1, int CIN1, int nb1,
               const float* __restrict__ w2, _Float16* __restrict__ h2, _Float16* __restrict__ l2, int OC2, int CIN2)
{
  int bb = blockIdx.x;
  if (bb < nb0)            prep_w_body(w0, h0, l0, OC0, CIN0, bb * 256 + threadIdx.x);
  else if (bb < nb0 + nb1) prep_w_body(w1, h1, l1, OC1, CIN1, (bb - nb0) * 256 + threadIdx.x);
  else                     prep_w_body(w2, h2, l2, OC2, CIN2, (bb - nb0 - nb1) * 256 + threadIdx.x);
}

// ---------- 3x3 conv, f16 MFMA; packed-padded inputs, gll staging (r18-best config) ----------
// SPLIT=3 (pre-topk): [.][258][258][64] hi+lo records; 48 gll tasks + edge copies.
// SPLIT=1 (tail): [.][258][258][32] hi records; 24 gll tasks + edge copies.
// Plateau dossier (r17-r21): occupancy 22-55% no effect; pipelining (manual x2,
// unroll-3 with/without setprio) null; OCB 48 null -> residual is the 2-phase
// stage->vmcnt(0)+barrier->compute structural drain (m233), not a pipe limit.
// This is the measured-best configuration: OCB=32 dcn / 64 t3, unroll-1, setprio.
// OMODE: 0 = NCHW f32 out, 1 = packed-padded hi/lo out, 3 = NHWC f16 hi only.
// MFMA 16x16x32 f16 (HW-verified r5-r21): A row=l&15 (oc), k=(l>>4)*8+j;
//   B col=l&15 (px); D col=l&15 (px), row=(l>>4)*4+reg (oc).
template<int CIN, int OC, int OCB, int ACT, int OMODE, int SPLIT>
__global__ __launch_bounds__(256)
void conv3x3_mfma_k(const _Float16* __restrict__ iH0, const _Float16* __restrict__ iL0,
                    const _Float16* __restrict__ iH1, const _Float16* __restrict__ iL1, int cin0,
                    const _Float16* __restrict__ wHi, const _Float16* __restrict__ wLo,
                    const float* __restrict__ bias,
                    float* __restrict__ outF, _Float16* __restrict__ oH, _Float16* __restrict__ oL)
{
  constexpr int NOF  = OCB / 16;
  constexpr int NAQ  = (SPLIT == 3) ? NOF : 1;
  constexpr int REC  = (SPLIT == 3) ? 64 : 32;
  constexpr int nOcg = OC / OCB;
  __shared__ _Float16 sB[6 * 66 * REC];

  const int l  = threadIdx.x & 63;
  const int wv = threadIdx.x >> 6;

  const int bid = blockIdx.x;
  const int xcd = bid & 7, q = bid >> 3;
  const int ocg  = q % nOcg;
  const int tIdx = (q / nOcg) * 8 + xcd;
  const int b   = tIdx >> 8;
  const int x0  = ((tIdx >> 6) & 3) * 64;
  const int y0  = (tIdx & 63) * 4;
  const int oc0 = ocg * OCB;

  float4v accP[NOF][4];
  float4v accQ[NAQ][4];
  #pragma unroll
  for (int j = 0; j < NOF; ++j)
    #pragma unroll
    for (int f = 0; f < 4; ++f)
      accP[j][f] = (float4v){0.f, 0.f, 0.f, 0.f};
  #pragma unroll
  for (int j = 0; j < NAQ; ++j)
    #pragma unroll
    for (int f = 0; f < 4; ++f)
      accQ[j][f] = (float4v){0.f, 0.f, 0.f, 0.f};

  const int k8  = (l >> 4) * 8;
  const int ocl = l & 15;
  const int rowy = y0 + wv;

  #pragma unroll 1
  for (int cc = 0; cc < CIN; cc += 32) {
    if constexpr (SPLIT == 3) {
      const _Float16* cb = (cc < cin0 ? iH0 : iH1) + (size_t)b * (PREC * 64);
      __syncthreads();
      // 48 gll tasks: 6 rows x 8 px-groups (8 px x 8 slots); 12 per wave
      #pragma unroll
      for (int k = 0; k < 12; ++k) {
        int t = wv + 4 * k;
        int r = t >> 3, s = t & 7;
        const _Float16* src = cb
            + (((size_t)(y0 + r) * PW) + (x0 + s * 8 + (l >> 3))) * 64
            + ((l & 7) ^ (l >> 3)) * 8;
        gload_lds16(src, &sB[(r * 66 + s * 8) * 64]);
      }
      #pragma unroll
      for (int rr = wv; rr < 6; rr += 4) {
        if (l < 16) {
          int pxo = l >> 3, slot = l & 7;
          const _Float16* src = cb
              + (((size_t)(y0 + rr) * PW) + (x0 + 64 + pxo)) * 64 + (slot ^ pxo) * 8;
          half8v v = *(const half8v*)src;
          *(half8v*)&sB[(rr * 66 + 64 + pxo) * 64 + slot * 8] = v;
        }
      }
      __syncthreads();
    } else {
      const _Float16* cb = iH0 + (size_t)(b * (CIN >> 5) + (cc >> 5)) * (PREC * 32);
      __syncthreads();
      // 24 gll tasks: 6 rows x 4 px-groups (16 px x 4 slots); 6 per wave
      #pragma unroll
      for (int k = 0; k < 6; ++k) {
        int t = wv + 4 * k;
        int r = t >> 2, s = t & 3;
        const _Float16* src = cb
            + (((size_t)(y0 + r) * PW) + (x0 + s * 16 + (l >> 2))) * 32
            + ((l & 3) ^ ((l >> 2) & 3)) * 8;
        gload_lds16(src, &sB[(r * 66 + s * 16) * 32]);
      }
      #pragma unroll
      for (int rr = wv; rr < 6; rr += 4) {
        if (l < 8) {
          int pxo = l >> 2, slot = l & 3;
          const _Float16* src = cb
              + (((size_t)(y0 + rr) * PW) + (x0 + 64 + pxo)) * 32 + (slot ^ pxo) * 8;
          half8v v = *(const half8v*)src;
          *(half8v*)&sB[(rr * 66 + 64 + pxo) * 32 + slot * 8] = v;
        }
      }
      __syncthreads();
    }

    #pragma unroll 1
    for (int tap = 0; tap < 9; ++tap) {
      const int dy = tap / 3, dx = tap - 3 * (tap / 3);
      half8v ah[NOF], aq[NAQ];
      const _Float16* hp = wHi + ((size_t)tap * OC + oc0 + ocl) * CIN + cc + k8;
      #pragma unroll
      for (int j = 0; j < NOF; ++j)
        ah[j] = *(const half8v*)(hp + (size_t)j * 16 * CIN);
      if constexpr (SPLIT == 3) {
        const _Float16* lp = wLo + ((size_t)tap * OC + oc0 + ocl) * CIN + cc + k8;
        #pragma unroll
        for (int j = 0; j < NOF; ++j)
          aq[j] = *(const half8v*)(lp + (size_t)j * 16 * CIN);
      }
      const int px = ocl + dx;
      if constexpr (SPLIT == 3) {
        const int rbase = ((wv + dy) * 66 + px) * 64;
        const int clsH = (l >> 4) ^ (px & 7);
        const int clsQ = ((l >> 4) + 4) ^ (px & 7);
        __builtin_amdgcn_s_setprio(1);
        #pragma unroll
        for (int f = 0; f < 4; ++f) {
          half8v bh = *(const half8v*)&sB[rbase + f * 1024 + clsH * 8];
          half8v bq = *(const half8v*)&sB[rbase + f * 1024 + clsQ * 8];
          #pragma unroll
          for (int j = 0; j < NOF; ++j) {
            accP[j][f] = __builtin_amdgcn_mfma_f32_16x16x32_f16(ah[j], bh, accP[j][f], 0, 0, 0);
            accQ[j][f] = __builtin_amdgcn_mfma_f32_16x16x32_f16(ah[j], bq, accQ[j][f], 0, 0, 0);
            accQ[j][f] = __builtin_amdgcn_mfma_f32_16x16x32_f16(aq[j], bh, accQ[j][f], 0, 0, 0);
          }
        }
        __builtin_amdgcn_s_setprio(0);
      } else {
        const int rbase = ((wv + dy) * 66 + px) * 32;
        const int clsH = ((l >> 4) ^ px) & 3;
        __builtin_amdgcn_s_setprio(1);
        #pragma unroll
        for (int f = 0; f < 4; ++f) {
          half8v bh = *(const half8v*)&sB[rbase + f * 512 + clsH * 8];
          #pragma unroll
          for (int j = 0; j < NOF; ++j)
            accP[j][f] = __builtin_amdgcn_mfma_f32_16x16x32_f16(ah[j], bh, accP[j][f], 0, 0, 0);
        }
        __builtin_amdgcn_s_setprio(0);
      }
    }
  }

  // ---- epilogue: D col=l&15 (px), row=(l>>4)*4+reg (oc) ----
  #pragma unroll
  for (int j = 0; j < NOF; ++j)
    #pragma unroll
    for (int f = 0; f < 4; ++f) {
      const int px  = x0 + f * 16 + ocl;
      const int occ = oc0 + j * 16 + (l >> 4) * 4;
      float vv4[4];
      #pragma unroll
      for (int r = 0; r < 4; ++r) {
        float bv = bias ? bias[occ + r] : 0.f;
        float vv = accP[j][f][r] + bv;
        if constexpr (SPLIT == 3) vv += accQ[j][f][r] * (1.0f / 2048.0f);
        vv4[r] = apply_act<ACT>(vv);
      }
      if constexpr (OMODE == 0) {
        #pragma unroll
        for (int r = 0; r < 4; ++r)
          outF[((size_t)(b * OC + occ + r) * H + rowy) * W + px] = vv4[r];
      } else if constexpr (OMODE == 1) {
        __attribute__((aligned(8))) _Float16 hv[4], lv[4];
        #pragma unroll
        for (int r = 0; r < 4; ++r) {
          _Float16 h = (_Float16)vv4[r];
          hv[r] = h;
          lv[r] = (_Float16)((vv4[r] - (float)h) * 2048.0f);
        }
        size_t rec = (size_t)b * PREC + (size_t)(rowy + 1) * PW + px + 1;
        *(half4v*)&oH[rec * 64 + occ]      = *(half4v*)&hv[0];
        *(half4v*)&oH[rec * 64 + 32 + occ] = *(half4v*)&lv[0];
      } else {
        __attribute__((aligned(8))) _Float16 hv[4];
        #pragma unroll
        for (int r = 0; r < 4; ++r) hv[r] = (_Float16)vv4[r];
        size_t ob = ((size_t)b * HW + (size_t)rowy * W + px) * OC + occ;
        *(half4v*)&oH[ob] = *(half4v*)&hv[0];
      }
    }
}

// ---------- 1x1 conv: NHWC f16 in -> packed-padded chunked f16 hi out ----------
template<int CIN, int OCB, int ACT>
__global__ __launch_bounds__(256)
void conv1x1_nhwc_k(const _Float16* __restrict__ in, const float* __restrict__ w,
                    _Float16* __restrict__ oP, int OC)
{
  __shared__ __align__(16) float sW[OCB][CIN];
  const int b   = blockIdx.y;
  const int oc0 = blockIdx.z * OCB;
  for (int t = threadIdx.x; t < OCB * CIN; t += 256)
    sW[t / CIN][t % CIN] = w[(size_t)(oc0 + t / CIN) * CIN + (t % CIN)];
  __syncthreads();

  const int pb = blockIdx.x * 1024 + threadIdx.x;    // 4 px at stride 256
  float acc[OCB][4];
  #pragma unroll
  for (int o = 0; o < OCB; ++o)
    #pragma unroll
    for (int i = 0; i < 4; ++i) acc[o][i] = 0.f;

  #pragma unroll 1
  for (int c0 = 0; c0 < CIN; c0 += 8) {
    float v[4][8];
    #pragma unroll
    for (int i = 0; i < 4; ++i) {
      const _Float16* ip = in + ((size_t)b * HW + pb + i * 256) * CIN + c0;
      half8v hv8 = *(const half8v*)ip;
      #pragma unroll
      for (int j = 0; j < 8; ++j) v[i][j] = (float)hv8[j];
    }
    #pragma unroll
    for (int o = 0; o < OCB; ++o) {
      const float4 w0 = *(const float4*)&sW[o][c0];
      const float4 w1 = *(const float4*)&sW[o][c0 + 4];
      #pragma unroll
      for (int i = 0; i < 4; ++i) {
        acc[o][i] += v[i][0]*w0.x + v[i][1]*w0.y + v[i][2]*w0.z + v[i][3]*w0.w
                   + v[i][4]*w1.x + v[i][5]*w1.y + v[i][6]*w1.z + v[i][7]*w1.w;
      }
    }
  }
  #pragma unroll
  for (int i = 0; i < 4; ++i) {
    __attribute__((aligned(16))) _Float16 hv[OCB];
    #pragma unroll
    for (int o = 0; o < OCB; ++o)
      hv[o] = (_Float16)apply_act<ACT>(acc[o][i]);
    int p = pb + i * 256;
    int y = p >> 8, xcol = p & 255;
    size_t rec = (size_t)(b * (OC >> 5) + (oc0 >> 5)) * PREC + (size_t)(y + 1) * PW + xcol + 1;
    #pragma unroll
    for (int j = 0; j < OCB / 8; ++j)
      *(half8v*)&oP[rec * 32 + (oc0 & 31) + j * 8] = *(half8v*)&hv[j * 8];
  }
}

// ---------- corr + top-3, 2 px/thread float2 (jax tie-break: lower index wins) ----------
__global__ __launch_bounds__(256)
void corr_topk_k(const float* __restrict__ warp, const float* __restrict__ x,
                 int* __restrict__ idxo)
{
  const int p2 = (blockIdx.x * 256 + threadIdx.x) * 2;
  const int b = blockIdx.y;
  float corr[9][2];
  #pragma unroll
  for (int o = 0; o < 9; ++o) { corr[o][0] = 0.f; corr[o][1] = 0.f; }
  #pragma unroll 1
  for (int c = 0; c < 32; ++c) {
    float2 xv = *(const float2*)&x[((size_t)b * 32 + c) * HW + p2];
    const float* wp = warp + ((size_t)b * 288 + (size_t)c * 9) * HW + p2;
    #pragma unroll
    for (int o = 0; o < 9; ++o) {
      float2 wv = *(const float2*)&wp[(size_t)o * HW];
      corr[o][0] += wv.x * xv.x;
      corr[o][1] += wv.y * xv.y;
    }
  }
  int2 packs;
  #pragma unroll
  for (int i = 0; i < 2; ++i) {
    unsigned mask = 0;
    int packed = 0;
    #pragma unroll
    for (int t = 0; t < 3; ++t) {
      float best = -INFINITY; int bi = 0;
      #pragma unroll
      for (int o = 0; o < 9; ++o) {
        bool take = (((mask >> o) & 1u) == 0u) && (corr[o][i] > best);
        best = take ? corr[o][i] : best;
        bi   = take ? o          : bi;
      }
      mask   |= 1u << bi;
      packed |= bi << (4 * t);
    }
    ((int*)&packs)[i] = packed;
  }
  *(int2*)&idxo[(size_t)b * HW + p2] = packs;
}

// ---------- gather selected warps + 3x3 conv with w_sel; out packed-padded f16 hi ----------
__global__ __launch_bounds__(256)
void selconv_k(const float* __restrict__ warp, const int* __restrict__ idxp,
               const float* __restrict__ wsel, const float* __restrict__ bsel,
               _Float16* __restrict__ oP)
{
  const int tx = threadIdx.x & 31, ty = threadIdx.x >> 5;
  const int px = blockIdx.x * 32 + tx;
  const int py = blockIdx.y * 8 + ty;
  const int b  = blockIdx.z;

  int  nidx[9];
  bool nval[9];
  int  qoff[9];
  #pragma unroll
  for (int kh = 0; kh < 3; ++kh)
    #pragma unroll
    for (int kw = 0; kw < 3; ++kw) {
      int k = kh * 3 + kw;
      int qy = py + kh - 1, qx = px + kw - 1;
      nval[k] = (qy >= 0 && qy < H && qx >= 0 && qx < W);
      qoff[k] = qy * W + qx;
      nidx[k] = nval[k] ? idxp[(size_t)b * HW + qoff[k]] : 0;
    }

  float ws27[27];
  #pragma unroll
  for (int i = 0; i < 27; ++i) ws27[i] = wsel[i];
  const float bs = bsel[0];

  float arr[32];
  #pragma unroll 1
  for (int c = 0; c < 32; ++c) {
    float acc = bs;
    const float* wb = warp + ((size_t)b * 288 + (size_t)c * 9) * HW;
    #pragma unroll
    for (int k = 0; k < 9; ++k) {
      if (nval[k]) {
        int pk = nidx[k];
        #pragma unroll
        for (int t = 0; t < 3; ++t) {
          int o = (pk >> (4 * t)) & 15;
          acc += ws27[t * 9 + k] * wb[(size_t)o * HW + qoff[k]];
        }
      }
    }
    arr[c] = acc;
  }

  __attribute__((aligned(16))) _Float16 hv[32];
  #pragma unroll
  for (int c = 0; c < 32; ++c) hv[c] = (_Float16)arr[c];
  size_t rec = (size_t)b * PREC + (size_t)(py + 1) * PW + px + 1;
  #pragma unroll
  for (int j = 0; j < 4; ++j)
    *(half8v*)&oP[rec * 32 + j * 8] = *(half8v*)&hv[j * 8];
}

// ---------- launch ----------
extern "C" void kernel_launch(void* const* d_in, const int* in_sizes, int n_in,
                              void* d_out, int out_size, void* d_ws, size_t ws_size,
                              hipStream_t stream) {
  const float* x      = (const float*)d_in[0];
  const float* key    = (const float*)d_in[1];
  const float* w_off1 = (const float*)d_in[2];
  const float* b_off1 = (const float*)d_in[3];
  const float* w_off2 = (const float*)d_in[4];
  const float* b_off2 = (const float*)d_in[5];
  const float* w_dcn  = (const float*)d_in[6];
  const float* b_dcn  = (const float*)d_in[7];
  const float* w_sel  = (const float*)d_in[8];
  const float* b_sel  = (const float*)d_in[9];
  const float* w_t1   = (const float*)d_in[10];
  const float* w_t2   = (const float*)d_in[11];
  const float* w_t3   = (const float*)d_in[12];
  const float* w_t4   = (const float*)d_in[13];
  const float* w_t5   = (const float*)d_in[14];

  // ---- workspace layout (peak ~185.74 MB; proven r17-r21) ----
  char* ws = (char*)d_ws;
  float* warp = (float*)(ws);                                // [2,288,HW] f32, [0, 150994944)
  _Float16* xP   = (_Float16*)(ws);                          // [0, 17040384)
  _Float16* o1P  = (_Float16*)(ws + 17040384);               // [17040384, 34080768)
  _Float16* w1H  = (_Float16*)(ws + 34080768);
  _Float16* w1L  = w1H + 18432;
  _Float16* w2H  = w1L + 18432;
  _Float16* w2L  = w2H + 9216;
  _Float16* wdH  = (_Float16*)(ws + 150994944);
  _Float16* wdL  = wdH + 165888;
  _Float16* keyP = (_Float16*)(ws + 151658496);
  _Float16* o2P  = (_Float16*)(ws + 168698880);
  int*      idxb = (int*)(ws + 150994944);
  _Float16* kwP  = (_Float16*)(ws + 151658496);
  _Float16* twB  = (_Float16*)(ws + 160178688);
  _Float16* t1H_w = twB;
  _Float16* t1L_w = twB + 9216;
  _Float16* t3H_w = twB + 18432;
  _Float16* t3L_w = twB + 165888;
  _Float16* t5H_w = twB + 313344;
  _Float16* t5L_w = twB + 322560;
  _Float16* y1  = (_Float16*)(ws);
  _Float16* t2P = (_Float16*)(ws + 16777216);
  _Float16* t4P = (_Float16*)(ws + 58720256);
  _Float16* y3  = (_Float16*)(ws + 83886080);
  float* out = (float*)d_out;

  dim3 blk(256);

  zero_border64_k<<<dim3(5, 8), blk, 0, stream>>>(xP, keyP, o1P, o2P);
  pack2_k<<<dim3(256, 2, 2), blk, 0, stream>>>(x, xP, key, keyP);
  prep3_w_k<<<dim3(756), blk, 0, stream>>>(
      w_off1, w1H, w1L, 32, 64, 72,
      w_off2, w2H, w2L, 32, 32, 36,
      w_dcn,  wdH, wdL, 288, 64);

  conv3x3_mfma_k<64, 32, 32, 1, 1, 3><<<dim3(512), blk, 0, stream>>>(
      xP, nullptr, keyP, nullptr, 32, w1H, w1L, b_off1, nullptr, o1P, nullptr);
  conv3x3_mfma_k<32, 32, 32, 1, 1, 3><<<dim3(512), blk, 0, stream>>>(
      o1P, nullptr, nullptr, nullptr, 32, w2H, w2L, b_off2, nullptr, o2P, nullptr);
  conv3x3_mfma_k<64, 288, 32, 0, 0, 3><<<dim3(4608), blk, 0, stream>>>(
      keyP, nullptr, o2P, nullptr, 32, wdH, wdL, b_dcn, warp, nullptr, nullptr);
  corr_topk_k<<<dim3(128, 2), blk, 0, stream>>>(warp, x, idxb);
  zero_border32_k<<<dim3(5, 2), blk, 0, stream>>>(kwP, PREC, kwP, PREC, kwP, PREC, kwP, PREC);
  selconv_k<<<dim3(8, 32, 2), blk, 0, stream>>>(warp, idxb, w_sel, b_sel, kwP);

  zero_border32_k<<<dim3(5, 8), blk, 0, stream>>>(
      t2P, 4 * PREC, t2P + PREC * 32, 4 * PREC, t2P + 2 * PREC * 32, 4 * PREC, t2P + 3 * PREC * 32, 4 * PREC);
  zero_border32_k<<<dim3(5, 2), blk, 0, stream>>>(t4P, PREC, t4P, PREC, t4P, PREC, t4P, PREC);
  prep3_w_k<<<dim3(648), blk, 0, stream>>>(
      w_t1, t1H_w, t1L_w, 32, 32, 36,
      w_t3, t3H_w, t3L_w, 128, 128, 576,
      w_t5, t5H_w, t5L_w, 32, 32);

  conv3x3_mfma_k<32, 32, 32, 2, 3, 1><<<dim3(512), blk, 0, stream>>>(
      kwP, nullptr, nullptr, nullptr, 32, t1H_w, t1L_w, nullptr, nullptr, y1, nullptr);
  conv1x1_nhwc_k<32, 16, 2><<<dim3(64, 2, 8), blk, 0, stream>>>(y1, w_t2, t2P, 128);
  conv3x3_mfma_k<128, 128, 64, 2, 3, 1><<<dim3(1024), blk, 0, stream>>>(
      t2P, nullptr, nullptr, nullptr, 128, t3H_w, t3L_w, nullptr, nullptr, y3, nullptr);
  conv1x1_nhwc_k<128, 16, 2><<<dim3(64, 2, 2), blk, 0, stream>>>(y3, w_t4, t4P, 32);
  conv3x3_mfma_k<32, 32, 32, 0, 0, 1><<<dim3(512), blk, 0, stream>>>(
      t4P, nullptr, nullptr, nullptr, 32, t5H_w, t5L_w, nullptr, out, nullptr, nullptr);
}